// Round 1
// baseline (383.139 us; speedup 1.0000x reference)
//
#include <hip/hip_runtime.h>

// ---------------------------------------------------------------------------
// SelfAttention with KV cache, MI355X (gfx950).
// B=4, T=2048, C=1024, T_PAST=2048, T_TOT=4096.
// Mask is tril(ones(T, T_total)) -> row t attends j<=t only => only past_k/v.
// Pipeline (all on `stream`, deterministic):
//   1. convert x, Wq, Wk, Wv -> bf16 in ws
//   2. copy past_v -> outV[:, 0:2048)
//   3. Q = (x Wq^T + bq)/32 -> bf16 in ws        (MFMA GEMM)
//   4. S = Q_scaled . past_k^T -> f32, stored in the d_out K region (scratch)
//   5. row softmax in place (reads cols [0,t], writes full 2048 row, 0 beyond t)
//   6. out = P . past_v                           (MFMA GEMM, V transposed in LDS)
//   7. copy past_k -> outK[:, 0:2048); K_new, V_new projections -> rows [2048,4096)
// Step 7 overwrites the S scratch only after step 6 consumed it (stream order).
// ---------------------------------------------------------------------------

typedef __bf16 bf16x8 __attribute__((ext_vector_type(8)));
typedef float f32x4 __attribute__((ext_vector_type(4)));

#define BB   4
#define TQ   2048
#define CD   1024
#define TPAST 2048
#define TTOT 4096
#define MROWS (BB * TQ)        // 8192

__device__ __forceinline__ unsigned short f32_to_bf16u(float f) {
  unsigned int u = __float_as_uint(f);
  u += 0x7FFFu + ((u >> 16) & 1u);       // RNE
  return (unsigned short)(u >> 16);
}
__device__ __forceinline__ unsigned int pack_bf16(float a, float b) {
  return (unsigned int)f32_to_bf16u(a) | ((unsigned int)f32_to_bf16u(b) << 16);
}

// ---- f32 -> bf16 bulk convert (vectorized: float4 in, uint2 out) -----------
__global__ __launch_bounds__(256) void cvt_f32_bf16_kernel(
    const float* __restrict__ src, unsigned short* __restrict__ dst, int n4) {
  int i = blockIdx.x * 256 + threadIdx.x;
  if (i >= n4) return;
  float4 f = ((const float4*)src)[i];
  uint2 o;
  o.x = pack_bf16(f.x, f.y);
  o.y = pack_bf16(f.z, f.w);
  ((uint2*)dst)[i] = o;
}

// ---- copy past (4,2048,1024) into cache region (4,4096,1024) rows [0,2048) -
__global__ __launch_bounds__(256) void copy_past_kernel(
    const float* __restrict__ src, float* __restrict__ dst) {
  int i = blockIdx.x * 256 + threadIdx.x;      // float4 units, 4*2048*1024/4 total
  int b = i >> 19;                             // 524288 units per batch
  int rem = i & 524287;
  ((float4*)dst)[(size_t)b * 1048576 + rem] = ((const float4*)src)[i];
}

// ---- projection GEMM: Y = x @ W^T + b ; M=8192, N=1024, K=1024 -------------
// MODE 0: Y -> bf16 Q (scaled by 1/32).  MODE 1/2: Y -> f32 cache rows 2048+.
// Tile 128x128, BK=32, 4 waves (2x2), each wave 64x64 = 4x4 MFMA frags.
template <int MODE>
__global__ __launch_bounds__(256) void proj_gemm(
    const unsigned short* __restrict__ A,   // x bf16 [8192][1024]
    const unsigned short* __restrict__ W,   // W bf16 [1024][1024] (row-major)
    const float* __restrict__ bias,         // [1024]
    unsigned short* __restrict__ outQ,      // MODE 0
    float* __restrict__ outF) {             // MODE 1/2: cache region base
  __shared__ unsigned short sA[128 * 40];   // +8 pad: 80B row stride, 2-way max
  __shared__ unsigned short sB[128 * 40];
  const int tm = blockIdx.x * 128, tn = blockIdx.y * 128;
  const int tid = threadIdx.x, lane = tid & 63, wv = tid >> 6;
  const int wr = wv >> 1, wc = wv & 1;
  const int lrow = tid >> 2, lseg = tid & 3;
  f32x4 acc[4][4] = {};
  for (int k0 = 0; k0 < CD; k0 += 32) {
#pragma unroll
    for (int it = 0; it < 2; ++it) {
      int r = lrow + it * 64;
      *(uint4*)&sA[r * 40 + lseg * 8] =
          *(const uint4*)&A[(size_t)(tm + r) * CD + k0 + lseg * 8];
      *(uint4*)&sB[r * 40 + lseg * 8] =
          *(const uint4*)&W[(size_t)(tn + r) * CD + k0 + lseg * 8];
    }
    __syncthreads();
    const int koff = (lane >> 4) * 8;
    bf16x8 af[4], bg[4];
#pragma unroll
    for (int i = 0; i < 4; ++i)
      af[i] = *(const bf16x8*)&sA[(wr * 64 + i * 16 + (lane & 15)) * 40 + koff];
#pragma unroll
    for (int i = 0; i < 4; ++i)
      bg[i] = *(const bf16x8*)&sB[(wc * 64 + i * 16 + (lane & 15)) * 40 + koff];
#pragma unroll
    for (int mi = 0; mi < 4; ++mi)
#pragma unroll
      for (int ni = 0; ni < 4; ++ni)
        acc[mi][ni] = __builtin_amdgcn_mfma_f32_16x16x32_bf16(
            af[mi], bg[ni], acc[mi][ni], 0, 0, 0);
    __syncthreads();
  }
  const int rsub = (lane >> 4) * 4, csub = lane & 15;
#pragma unroll
  for (int mi = 0; mi < 4; ++mi)
#pragma unroll
    for (int ni = 0; ni < 4; ++ni) {
      int gc = tn + wc * 64 + ni * 16 + csub;
      float bv = bias[gc];
#pragma unroll
      for (int r = 0; r < 4; ++r) {
        int gr = tm + wr * 64 + mi * 16 + rsub + r;
        float v = acc[mi][ni][r] + bv;
        if (MODE == 0) {
          outQ[(size_t)gr * CD + gc] = f32_to_bf16u(v * 0.03125f);  // 1/sqrt(1024)
        } else {
          int b = gr >> 11, t = gr & (TQ - 1);
          outF[(size_t)b * (TTOT * CD) + (size_t)(TPAST + t) * CD + gc] = v;
        }
      }
    }
}

// ---- scores: S[b][t][s] = Q_scaled[b,t,:] . past_k[b,s,:] ------------------
// Tiles with s0 > t0+127 fully masked -> skipped (softmax never reads them).
__global__ __launch_bounds__(256) void score_gemm(
    const unsigned short* __restrict__ Q,   // bf16 [8192][1024], pre-scaled
    const float* __restrict__ pK,           // f32 [4][2048][1024]
    float* __restrict__ S) {                // f32 [4][2048][2048]
  const int t0 = blockIdx.x * 128, s0 = blockIdx.y * 128, b = blockIdx.z;
  if (s0 > t0 + 127) return;
  __shared__ unsigned short sA[128 * 40];
  __shared__ unsigned short sB[128 * 40];
  const int tid = threadIdx.x, lane = tid & 63, wv = tid >> 6;
  const int wr = wv >> 1, wc = wv & 1;
  const int lrow = tid >> 2, lseg = tid & 3;
  f32x4 acc[4][4] = {};
  for (int k0 = 0; k0 < CD; k0 += 32) {
#pragma unroll
    for (int it = 0; it < 2; ++it) {
      int r = lrow + it * 64;
      *(uint4*)&sA[r * 40 + lseg * 8] =
          *(const uint4*)&Q[(size_t)(b * TQ + t0 + r) * CD + k0 + lseg * 8];
      const float4* src =
          (const float4*)&pK[(size_t)(b * TPAST + s0 + r) * CD + k0 + lseg * 8];
      float4 f0 = src[0], f1 = src[1];
      uint4 o;
      o.x = pack_bf16(f0.x, f0.y); o.y = pack_bf16(f0.z, f0.w);
      o.z = pack_bf16(f1.x, f1.y); o.w = pack_bf16(f1.z, f1.w);
      *(uint4*)&sB[r * 40 + lseg * 8] = o;
    }
    __syncthreads();
    const int koff = (lane >> 4) * 8;
    bf16x8 af[4], bg[4];
#pragma unroll
    for (int i = 0; i < 4; ++i)
      af[i] = *(const bf16x8*)&sA[(wr * 64 + i * 16 + (lane & 15)) * 40 + koff];
#pragma unroll
    for (int i = 0; i < 4; ++i)
      bg[i] = *(const bf16x8*)&sB[(wc * 64 + i * 16 + (lane & 15)) * 40 + koff];
#pragma unroll
    for (int mi = 0; mi < 4; ++mi)
#pragma unroll
      for (int ni = 0; ni < 4; ++ni)
        acc[mi][ni] = __builtin_amdgcn_mfma_f32_16x16x32_bf16(
            af[mi], bg[ni], acc[mi][ni], 0, 0, 0);
    __syncthreads();
  }
  const int rsub = (lane >> 4) * 4, csub = lane & 15;
#pragma unroll
  for (int mi = 0; mi < 4; ++mi)
#pragma unroll
    for (int ni = 0; ni < 4; ++ni) {
      int gs = s0 + wc * 64 + ni * 16 + csub;
#pragma unroll
      for (int r = 0; r < 4; ++r) {
        int gt = t0 + wr * 64 + mi * 16 + rsub + r;
        S[(size_t)b * (TQ * TPAST) + (size_t)gt * TPAST + gs] = acc[mi][ni][r];
      }
    }
}

// ---- row softmax in place; reads cols [0,t], writes full 2048 (0 beyond t) -
__global__ __launch_bounds__(256) void softmax_kernel(float* __restrict__ S) {
  const int row = blockIdx.x;               // 0..8191
  const int b = row >> 11, t = row & (TQ - 1);
  float* p = S + (size_t)b * (TQ * TPAST) + (size_t)t * TPAST;
  const int tid = threadIdx.x, lane = tid & 63, wv = tid >> 6;
  __shared__ float red[8];
  const int base = tid * 8;
  float4 f0 = *(const float4*)&p[base];
  float4 f1 = *(const float4*)&p[base + 4];
  float v[8] = {f0.x, f0.y, f0.z, f0.w, f1.x, f1.y, f1.z, f1.w};
  float m = -3.0e38f;
#pragma unroll
  for (int i = 0; i < 8; ++i) {
    if (base + i > t) v[i] = -3.0e38f;      // masked/unwritten cols
    m = fmaxf(m, v[i]);
  }
#pragma unroll
  for (int off = 32; off >= 1; off >>= 1) m = fmaxf(m, __shfl_down(m, off));
  if (lane == 0) red[wv] = m;
  __syncthreads();
  if (tid == 0) red[4] = fmaxf(fmaxf(red[0], red[1]), fmaxf(red[2], red[3]));
  __syncthreads();
  const float rm = red[4];
  float e[8], s = 0.f;
#pragma unroll
  for (int i = 0; i < 8; ++i) {
    e[i] = (base + i <= t) ? __expf(v[i] - rm) : 0.f;
    s += e[i];
  }
#pragma unroll
  for (int off = 32; off >= 1; off >>= 1) s += __shfl_down(s, off);
  __syncthreads();
  if (lane == 0) red[wv] = s;
  __syncthreads();
  if (tid == 0) red[5] = red[0] + red[1] + red[2] + red[3];
  __syncthreads();
  const float inv = 1.f / red[5];
  f0.x = e[0] * inv; f0.y = e[1] * inv; f0.z = e[2] * inv; f0.w = e[3] * inv;
  f1.x = e[4] * inv; f1.y = e[5] * inv; f1.z = e[6] * inv; f1.w = e[7] * inv;
  *(float4*)&p[base] = f0;
  *(float4*)&p[base + 4] = f1;
}

// ---- out = P @ V ; per batch M=2048, N=1024, K=s up to t0+128 --------------
__global__ __launch_bounds__(256) void pv_gemm(
    const float* __restrict__ P,            // f32 [4][2048][2048] (post-softmax)
    const float* __restrict__ pV,           // f32 [4][2048][1024]
    float* __restrict__ O) {                // f32 [4][2048][1024]
  const int t0 = blockIdx.x * 128, c0 = blockIdx.y * 128, b = blockIdx.z;
  __shared__ unsigned short sA[128 * 40];   // P tile  [t][s]
  __shared__ unsigned short sVT[128 * 40];  // V^T tile [c][s]
  const int tid = threadIdx.x, lane = tid & 63, wv = tid >> 6;
  const int wr = wv >> 1, wc = wv & 1;
  const int lrow = tid >> 2, lseg = tid & 3;
  const int vsr = tid >> 5, vcs = tid & 31;
  f32x4 acc[4][4] = {};
  const int s_end = (t0 + 128 < TPAST) ? (t0 + 128) : TPAST;  // P==0 past t
  for (int s0 = 0; s0 < s_end; s0 += 32) {
#pragma unroll
    for (int it = 0; it < 2; ++it) {
      int r = lrow + it * 64;
      const float4* src = (const float4*)&P[(size_t)b * (TQ * TPAST) +
                                            (size_t)(t0 + r) * TPAST + s0 + lseg * 8];
      float4 f0 = src[0], f1 = src[1];
      uint4 o;
      o.x = pack_bf16(f0.x, f0.y); o.y = pack_bf16(f0.z, f0.w);
      o.z = pack_bf16(f1.x, f1.y); o.w = pack_bf16(f1.z, f1.w);
      *(uint4*)&sA[r * 40 + lseg * 8] = o;
    }
#pragma unroll
    for (int it = 0; it < 4; ++it) {        // V transpose into LDS
      int sr = vsr + it * 8;
      float4 f = *(const float4*)&pV[(size_t)(b * TPAST + s0 + sr) * CD + c0 + vcs * 4];
      sVT[(vcs * 4 + 0) * 40 + sr] = f32_to_bf16u(f.x);
      sVT[(vcs * 4 + 1) * 40 + sr] = f32_to_bf16u(f.y);
      sVT[(vcs * 4 + 2) * 40 + sr] = f32_to_bf16u(f.z);
      sVT[(vcs * 4 + 3) * 40 + sr] = f32_to_bf16u(f.w);
    }
    __syncthreads();
    const int koff = (lane >> 4) * 8;
    bf16x8 af[4], bg[4];
#pragma unroll
    for (int i = 0; i < 4; ++i)
      af[i] = *(const bf16x8*)&sA[(wr * 64 + i * 16 + (lane & 15)) * 40 + koff];
#pragma unroll
    for (int i = 0; i < 4; ++i)
      bg[i] = *(const bf16x8*)&sVT[(wc * 64 + i * 16 + (lane & 15)) * 40 + koff];
#pragma unroll
    for (int mi = 0; mi < 4; ++mi)
#pragma unroll
      for (int ni = 0; ni < 4; ++ni)
        acc[mi][ni] = __builtin_amdgcn_mfma_f32_16x16x32_bf16(
            af[mi], bg[ni], acc[mi][ni], 0, 0, 0);
    __syncthreads();
  }
  const int rsub = (lane >> 4) * 4, csub = lane & 15;
#pragma unroll
  for (int mi = 0; mi < 4; ++mi)
#pragma unroll
    for (int ni = 0; ni < 4; ++ni) {
      int gc = c0 + wc * 64 + ni * 16 + csub;
#pragma unroll
      for (int r = 0; r < 4; ++r) {
        int gt = t0 + wr * 64 + mi * 16 + rsub + r;
        O[(size_t)(b * TQ + gt) * CD + gc] = acc[mi][ni][r];
      }
    }
}

extern "C" void kernel_launch(void* const* d_in, const int* in_sizes, int n_in,
                              void* d_out, int out_size, void* d_ws, size_t ws_size,
                              hipStream_t stream) {
  const float* x  = (const float*)d_in[0];
  const float* pk = (const float*)d_in[1];
  const float* pv = (const float*)d_in[2];
  const float* Wq = (const float*)d_in[3];
  const float* bq = (const float*)d_in[4];
  const float* Wk = (const float*)d_in[5];
  const float* bk = (const float*)d_in[6];
  const float* Wv = (const float*)d_in[7];
  const float* bv = (const float*)d_in[8];

  float* out  = (float*)d_out;                       // (4,2048,1024)
  float* outK = out + (size_t)BB * TQ * CD;          // (4,4096,1024)
  float* outV = outK + (size_t)BB * TTOT * CD;       // (4,4096,1024)
  float* S = outK;  // 67.1MB scratch == K region size; overwritten in step 7

  unsigned short* xb  = (unsigned short*)d_ws;       // 8192*1024 bf16
  unsigned short* wqb = xb + (size_t)MROWS * CD;
  unsigned short* wkb = wqb + (size_t)CD * CD;
  unsigned short* wvb = wkb + (size_t)CD * CD;
  unsigned short* qb  = wvb + (size_t)CD * CD;       // 8192*1024 bf16

  // 1. conversions
  cvt_f32_bf16_kernel<<<MROWS * CD / 4 / 256, 256, 0, stream>>>(x, xb, MROWS * CD / 4);
  cvt_f32_bf16_kernel<<<CD * CD / 4 / 256, 256, 0, stream>>>(Wq, wqb, CD * CD / 4);
  cvt_f32_bf16_kernel<<<CD * CD / 4 / 256, 256, 0, stream>>>(Wk, wkb, CD * CD / 4);
  cvt_f32_bf16_kernel<<<CD * CD / 4 / 256, 256, 0, stream>>>(Wv, wvb, CD * CD / 4);
  // 2. past_v -> V cache rows [0,2048)
  copy_past_kernel<<<BB * TPAST * CD / 4 / 256, 256, 0, stream>>>(pv, outV);
  // 3. Q projection (scaled, bf16)
  proj_gemm<0><<<dim3(MROWS / 128, CD / 128), 256, 0, stream>>>(xb, wqb, bq, qb, nullptr);
  // 4. scores into S (K-region scratch)
  score_gemm<<<dim3(TQ / 128, TPAST / 128, BB), 256, 0, stream>>>(qb, pk, S);
  // 5. softmax rows in place
  softmax_kernel<<<BB * TQ, 256, 0, stream>>>(S);
  // 6. out = P @ past_v
  pv_gemm<<<dim3(TQ / 128, CD / 128, BB), 256, 0, stream>>>(S, pv, out);
  // 7. overwrite K region: past_k copy + K_new; V_new
  copy_past_kernel<<<BB * TPAST * CD / 4 / 256, 256, 0, stream>>>(pk, outK);
  proj_gemm<1><<<dim3(MROWS / 128, CD / 128), 256, 0, stream>>>(xb, wkb, bk, nullptr, outK);
  proj_gemm<2><<<dim3(MROWS / 128, CD / 128), 256, 0, stream>>>(xb, wvb, bv, nullptr, outV);
}

// Round 2
// 275.239 us; speedup vs baseline: 1.3920x; 1.3920x over previous
//
#include <hip/hip_runtime.h>

// ---------------------------------------------------------------------------
// SelfAttention with KV cache, MI355X (gfx950).
// B=4, T=2048, C=1024, T_PAST=2048, T_TOT=4096.
// Mask tril(ones(T, T_total)) -> row t attends j<=t only => only past_k/v.
// Pipeline:
//   1. convert x, Wq, Wk, Wv -> bf16 in ws
//   2. v_copy_transpose: past_v -> outV rows [0,2048)  AND  VT bf16 [b][c][s] in ws
//   3. Q = (x Wq^T + bq)/32 -> bf16 in ws        (MFMA GEMM)
//   4. S = Q_scaled . past_k^T -> f32, stored in d_out K region (scratch)
//   5. softmax: read f32 row, write bf16 row IN PLACE (zeros beyond col t)
//   6. out = P(bf16) @ VT(bf16)                  (MFMA GEMM, no transposes)
//   7. copy past_k -> outK[:,0:2048); K_new, V_new projections -> rows [2048,4096)
// Step 7 overwrites the S scratch only after step 6 consumed it (stream order).
// ---------------------------------------------------------------------------

typedef __bf16 bf16x8 __attribute__((ext_vector_type(8)));
typedef float f32x4 __attribute__((ext_vector_type(4)));

#define BB   4
#define TQ   2048
#define CD   1024
#define TPAST 2048
#define TTOT 4096
#define MROWS (BB * TQ)        // 8192

__device__ __forceinline__ unsigned short f32_to_bf16u(float f) {
  unsigned int u = __float_as_uint(f);
  u += 0x7FFFu + ((u >> 16) & 1u);       // RNE
  return (unsigned short)(u >> 16);
}
__device__ __forceinline__ unsigned int pack_bf16(float a, float b) {
  return (unsigned int)f32_to_bf16u(a) | ((unsigned int)f32_to_bf16u(b) << 16);
}

// ---- f32 -> bf16 bulk convert (vectorized: float4 in, uint2 out) -----------
__global__ __launch_bounds__(256) void cvt_f32_bf16_kernel(
    const float* __restrict__ src, unsigned short* __restrict__ dst, int n4) {
  int i = blockIdx.x * 256 + threadIdx.x;
  if (i >= n4) return;
  float4 f = ((const float4*)src)[i];
  uint2 o;
  o.x = pack_bf16(f.x, f.y);
  o.y = pack_bf16(f.z, f.w);
  ((uint2*)dst)[i] = o;
}

// ---- copy past (4,2048,1024) into cache region (4,4096,1024) rows [0,2048) -
__global__ __launch_bounds__(256) void copy_past_kernel(
    const float* __restrict__ src, float* __restrict__ dst) {
  int i = blockIdx.x * 256 + threadIdx.x;      // float4 units
  int b = i >> 19;                             // 524288 units per batch
  int rem = i & 524287;
  ((float4*)dst)[(size_t)b * 1048576 + rem] = ((const float4*)src)[i];
}

// ---- fused: past_v -> outV copy + bf16 transpose VT[b][c][s] ----------------
// Tile 32(s) x 128(c). LDS [s][c] pad 134 u16: write phase ~2-way, read phase
// conflict-free (24*sq + 3j + cc/2 covers all 32 banks, same-dword = broadcast).
#define TP_PAD 134
__global__ __launch_bounds__(256) void v_copy_transpose(
    const float* __restrict__ pV, float* __restrict__ outV,
    unsigned short* __restrict__ VT) {
  __shared__ unsigned short T[32 * TP_PAD];
  const int s0 = blockIdx.x * 32, c0 = blockIdx.y * 128, b = blockIdx.z;
  const int tid = threadIdx.x;
  const int s = tid >> 3, i8 = tid & 7;
  const float* src = &pV[(size_t)(b * TPAST + s0 + s) * CD + c0];
  float* dst = &outV[(size_t)b * (TTOT * CD) + (size_t)(s0 + s) * CD + c0];
#pragma unroll
  for (int k = 0; k < 4; ++k) {
    int c = k * 32 + i8 * 4;                   // per-instr: 8 lanes x 16B = 128B/row
    float4 f = *(const float4*)&src[c];
    *(float4*)&dst[c] = f;
    *(unsigned int*)&T[s * TP_PAD + c]     = pack_bf16(f.x, f.y);
    *(unsigned int*)&T[s * TP_PAD + c + 2] = pack_bf16(f.z, f.w);
  }
  __syncthreads();
  const int c = tid >> 2, sq = tid & 3;
#pragma unroll
  for (int ii = 0; ii < 2; ++ii) {
    int cc = c + ii * 64;
    unsigned short tmp[8];
#pragma unroll
    for (int j = 0; j < 8; ++j) tmp[j] = T[(sq * 8 + j) * TP_PAD + cc];
    *(uint4*)&VT[(size_t)(b * CD + c0 + cc) * TPAST + s0 + sq * 8] = *(uint4*)tmp;
  }
}

// ---- projection GEMM: Y = x @ W^T + b ; M=8192, N=1024, K=1024 -------------
// MODE 0: Y -> bf16 Q (scaled by 1/32).  MODE 1/2: Y -> f32 cache rows 2048+.
template <int MODE>
__global__ __launch_bounds__(256) void proj_gemm(
    const unsigned short* __restrict__ A,   // x bf16 [8192][1024]
    const unsigned short* __restrict__ W,   // W bf16 [1024][1024]
    const float* __restrict__ bias,
    unsigned short* __restrict__ outQ,      // MODE 0
    float* __restrict__ outF) {             // MODE 1/2: cache region base
  __shared__ unsigned short sA[128 * 40];
  __shared__ unsigned short sB[128 * 40];
  const int tm = blockIdx.x * 128, tn = blockIdx.y * 128;
  const int tid = threadIdx.x, lane = tid & 63, wv = tid >> 6;
  const int wr = wv >> 1, wc = wv & 1;
  const int lrow = tid >> 2, lseg = tid & 3;
  f32x4 acc[4][4] = {};
  for (int k0 = 0; k0 < CD; k0 += 32) {
#pragma unroll
    for (int it = 0; it < 2; ++it) {
      int r = lrow + it * 64;
      *(uint4*)&sA[r * 40 + lseg * 8] =
          *(const uint4*)&A[(size_t)(tm + r) * CD + k0 + lseg * 8];
      *(uint4*)&sB[r * 40 + lseg * 8] =
          *(const uint4*)&W[(size_t)(tn + r) * CD + k0 + lseg * 8];
    }
    __syncthreads();
    const int koff = (lane >> 4) * 8;
    bf16x8 af[4], bg[4];
#pragma unroll
    for (int i = 0; i < 4; ++i)
      af[i] = *(const bf16x8*)&sA[(wr * 64 + i * 16 + (lane & 15)) * 40 + koff];
#pragma unroll
    for (int i = 0; i < 4; ++i)
      bg[i] = *(const bf16x8*)&sB[(wc * 64 + i * 16 + (lane & 15)) * 40 + koff];
#pragma unroll
    for (int mi = 0; mi < 4; ++mi)
#pragma unroll
      for (int ni = 0; ni < 4; ++ni)
        acc[mi][ni] = __builtin_amdgcn_mfma_f32_16x16x32_bf16(
            af[mi], bg[ni], acc[mi][ni], 0, 0, 0);
    __syncthreads();
  }
  const int rsub = (lane >> 4) * 4, csub = lane & 15;
#pragma unroll
  for (int mi = 0; mi < 4; ++mi)
#pragma unroll
    for (int ni = 0; ni < 4; ++ni) {
      int gc = tn + wc * 64 + ni * 16 + csub;
      float bv = bias[gc];
#pragma unroll
      for (int r = 0; r < 4; ++r) {
        int gr = tm + wr * 64 + mi * 16 + rsub + r;
        float v = acc[mi][ni][r] + bv;
        if (MODE == 0) {
          outQ[(size_t)gr * CD + gc] = f32_to_bf16u(v * 0.03125f);  // 1/sqrt(1024)
        } else {
          int b = gr >> 11, t = gr & (TQ - 1);
          outF[(size_t)b * (TTOT * CD) + (size_t)(TPAST + t) * CD + gc] = v;
        }
      }
    }
}

// ---- scores: S[b][t][s] = Q_scaled[b,t,:] . past_k[b,s,:] ------------------
__global__ __launch_bounds__(256) void score_gemm(
    const unsigned short* __restrict__ Q,   // bf16 [8192][1024], pre-scaled
    const float* __restrict__ pK,           // f32 [4][2048][1024]
    float* __restrict__ S) {                // f32 [4][2048][2048]
  const int t0 = blockIdx.x * 128, s0 = blockIdx.y * 128, b = blockIdx.z;
  if (s0 > t0 + 127) return;
  __shared__ unsigned short sA[128 * 40];
  __shared__ unsigned short sB[128 * 40];
  const int tid = threadIdx.x, lane = tid & 63, wv = tid >> 6;
  const int wr = wv >> 1, wc = wv & 1;
  const int lrow = tid >> 2, lseg = tid & 3;
  f32x4 acc[4][4] = {};
  for (int k0 = 0; k0 < CD; k0 += 32) {
#pragma unroll
    for (int it = 0; it < 2; ++it) {
      int r = lrow + it * 64;
      *(uint4*)&sA[r * 40 + lseg * 8] =
          *(const uint4*)&Q[(size_t)(b * TQ + t0 + r) * CD + k0 + lseg * 8];
      const float4* src =
          (const float4*)&pK[(size_t)(b * TPAST + s0 + r) * CD + k0 + lseg * 8];
      float4 f0 = src[0], f1 = src[1];
      uint4 o;
      o.x = pack_bf16(f0.x, f0.y); o.y = pack_bf16(f0.z, f0.w);
      o.z = pack_bf16(f1.x, f1.y); o.w = pack_bf16(f1.z, f1.w);
      *(uint4*)&sB[r * 40 + lseg * 8] = o;
    }
    __syncthreads();
    const int koff = (lane >> 4) * 8;
    bf16x8 af[4], bg[4];
#pragma unroll
    for (int i = 0; i < 4; ++i)
      af[i] = *(const bf16x8*)&sA[(wr * 64 + i * 16 + (lane & 15)) * 40 + koff];
#pragma unroll
    for (int i = 0; i < 4; ++i)
      bg[i] = *(const bf16x8*)&sB[(wc * 64 + i * 16 + (lane & 15)) * 40 + koff];
#pragma unroll
    for (int mi = 0; mi < 4; ++mi)
#pragma unroll
      for (int ni = 0; ni < 4; ++ni)
        acc[mi][ni] = __builtin_amdgcn_mfma_f32_16x16x32_bf16(
            af[mi], bg[ni], acc[mi][ni], 0, 0, 0);
    __syncthreads();
  }
  const int rsub = (lane >> 4) * 4, csub = lane & 15;
#pragma unroll
  for (int mi = 0; mi < 4; ++mi)
#pragma unroll
    for (int ni = 0; ni < 4; ++ni) {
      int gs = s0 + wc * 64 + ni * 16 + csub;
#pragma unroll
      for (int r = 0; r < 4; ++r) {
        int gt = t0 + wr * 64 + mi * 16 + rsub + r;
        S[(size_t)b * (TQ * TPAST) + (size_t)gt * TPAST + gs] = acc[mi][ni][r];
      }
    }
}

// ---- row softmax: read f32 row, write bf16 row IN PLACE (first 4096B) ------
// All reads complete before the reduction barriers; writes only after. Masked
// cols (s > t) are written as bf16 zero so pv_gemm can read full tiles.
__global__ __launch_bounds__(256) void softmax_kernel(float* __restrict__ S) {
  const int row = blockIdx.x;               // 0..8191
  const int b = row >> 11, t = row & (TQ - 1);
  float* p = S + (size_t)b * (TQ * TPAST) + (size_t)t * TPAST;
  const int tid = threadIdx.x, lane = tid & 63, wv = tid >> 6;
  __shared__ float red[8];
  const int base = tid * 8;
  float4 f0 = *(const float4*)&p[base];
  float4 f1 = *(const float4*)&p[base + 4];
  float v[8] = {f0.x, f0.y, f0.z, f0.w, f1.x, f1.y, f1.z, f1.w};
  float m = -3.0e38f;
#pragma unroll
  for (int i = 0; i < 8; ++i) {
    if (base + i > t) v[i] = -3.0e38f;      // masked/unwritten cols
    m = fmaxf(m, v[i]);
  }
#pragma unroll
  for (int off = 32; off >= 1; off >>= 1) m = fmaxf(m, __shfl_down(m, off));
  if (lane == 0) red[wv] = m;
  __syncthreads();
  if (tid == 0) red[4] = fmaxf(fmaxf(red[0], red[1]), fmaxf(red[2], red[3]));
  __syncthreads();
  const float rm = red[4];
  float e[8], s = 0.f;
#pragma unroll
  for (int i = 0; i < 8; ++i) {
    e[i] = (base + i <= t) ? __expf(v[i] - rm) : 0.f;
    s += e[i];
  }
#pragma unroll
  for (int off = 32; off >= 1; off >>= 1) s += __shfl_down(s, off);
  __syncthreads();
  if (lane == 0) red[wv] = s;
  __syncthreads();
  if (tid == 0) red[5] = red[0] + red[1] + red[2] + red[3];
  __syncthreads();                           // also orders all reads before writes
  const float inv = 1.f / red[5];
  unsigned short ob[8];
#pragma unroll
  for (int i = 0; i < 8; ++i) ob[i] = f32_to_bf16u(e[i] * inv);
  *(uint4*)&((unsigned short*)p)[base] = *(uint4*)ob;
}

// ---- out = P(bf16) @ VT(bf16) ; per batch M=2048, N=1024(c), K=s -----------
__global__ __launch_bounds__(256) void pv_gemm(
    const unsigned short* __restrict__ Pb,  // bf16 rows at f32-row byte offsets
    const unsigned short* __restrict__ VT,  // bf16 [4][1024][2048]
    float* __restrict__ O) {                // f32 [4][2048][1024]
  const int t0 = blockIdx.x * 128, c0 = blockIdx.y * 128, b = blockIdx.z;
  __shared__ unsigned short sA[128 * 40];
  __shared__ unsigned short sB[128 * 40];
  const int tid = threadIdx.x, lane = tid & 63, wv = tid >> 6;
  const int wr = wv >> 1, wc = wv & 1;
  const int lrow = tid >> 2, lseg = tid & 3;
  f32x4 acc[4][4] = {};
  const int s_end = (t0 + 128 < TPAST) ? (t0 + 128) : TPAST;  // P==0 past t
  for (int s0 = 0; s0 < s_end; s0 += 32) {
#pragma unroll
    for (int it = 0; it < 2; ++it) {
      int r = lrow + it * 64;
      // P bf16 row for (b, t0+r) lives at u16 offset 2*(f32 row offset)
      const unsigned short* prow =
          Pb + 2 * ((size_t)b * (TQ * TPAST) + (size_t)(t0 + r) * TPAST);
      *(uint4*)&sA[r * 40 + lseg * 8] = *(const uint4*)&prow[s0 + lseg * 8];
      *(uint4*)&sB[r * 40 + lseg * 8] =
          *(const uint4*)&VT[(size_t)(b * CD + c0 + r) * TPAST + s0 + lseg * 8];
    }
    __syncthreads();
    const int koff = (lane >> 4) * 8;
    bf16x8 af[4], bg[4];
#pragma unroll
    for (int i = 0; i < 4; ++i)
      af[i] = *(const bf16x8*)&sA[(wr * 64 + i * 16 + (lane & 15)) * 40 + koff];
#pragma unroll
    for (int i = 0; i < 4; ++i)
      bg[i] = *(const bf16x8*)&sB[(wc * 64 + i * 16 + (lane & 15)) * 40 + koff];
#pragma unroll
    for (int mi = 0; mi < 4; ++mi)
#pragma unroll
      for (int ni = 0; ni < 4; ++ni)
        acc[mi][ni] = __builtin_amdgcn_mfma_f32_16x16x32_bf16(
            af[mi], bg[ni], acc[mi][ni], 0, 0, 0);
    __syncthreads();
  }
  const int rsub = (lane >> 4) * 4, csub = lane & 15;
#pragma unroll
  for (int mi = 0; mi < 4; ++mi)
#pragma unroll
    for (int ni = 0; ni < 4; ++ni) {
      int gc = c0 + wc * 64 + ni * 16 + csub;
#pragma unroll
      for (int r = 0; r < 4; ++r) {
        int gt = t0 + wr * 64 + mi * 16 + rsub + r;
        O[(size_t)(b * TQ + gt) * CD + gc] = acc[mi][ni][r];
      }
    }
}

extern "C" void kernel_launch(void* const* d_in, const int* in_sizes, int n_in,
                              void* d_out, int out_size, void* d_ws, size_t ws_size,
                              hipStream_t stream) {
  const float* x  = (const float*)d_in[0];
  const float* pk = (const float*)d_in[1];
  const float* pv = (const float*)d_in[2];
  const float* Wq = (const float*)d_in[3];
  const float* bq = (const float*)d_in[4];
  const float* Wk = (const float*)d_in[5];
  const float* bk = (const float*)d_in[6];
  const float* Wv = (const float*)d_in[7];
  const float* bv = (const float*)d_in[8];

  float* out  = (float*)d_out;                       // (4,2048,1024)
  float* outK = out + (size_t)BB * TQ * CD;          // (4,4096,1024)
  float* outV = outK + (size_t)BB * TTOT * CD;       // (4,4096,1024)
  float* S = outK;  // 67.1MB scratch == K region size; overwritten in step 7

  unsigned short* xb  = (unsigned short*)d_ws;       // 8192*1024 bf16
  unsigned short* wqb = xb + (size_t)MROWS * CD;
  unsigned short* wkb = wqb + (size_t)CD * CD;
  unsigned short* wvb = wkb + (size_t)CD * CD;
  unsigned short* qb  = wvb + (size_t)CD * CD;       // 8192*1024 bf16
  unsigned short* vtb = qb + (size_t)MROWS * CD;     // 4*1024*2048 bf16 (V^T)

  // 1. conversions
  cvt_f32_bf16_kernel<<<MROWS * CD / 4 / 256, 256, 0, stream>>>(x, xb, MROWS * CD / 4);
  cvt_f32_bf16_kernel<<<CD * CD / 4 / 256, 256, 0, stream>>>(Wq, wqb, CD * CD / 4);
  cvt_f32_bf16_kernel<<<CD * CD / 4 / 256, 256, 0, stream>>>(Wk, wkb, CD * CD / 4);
  cvt_f32_bf16_kernel<<<CD * CD / 4 / 256, 256, 0, stream>>>(Wv, wvb, CD * CD / 4);
  // 2. past_v -> outV rows [0,2048) + VT bf16 transpose
  v_copy_transpose<<<dim3(TPAST / 32, CD / 128, BB), 256, 0, stream>>>(pv, outV, vtb);
  // 3. Q projection (scaled, bf16)
  proj_gemm<0><<<dim3(MROWS / 128, CD / 128), 256, 0, stream>>>(xb, wqb, bq, qb, nullptr);
  // 4. scores into S (K-region scratch)
  score_gemm<<<dim3(TQ / 128, TPAST / 128, BB), 256, 0, stream>>>(qb, pk, S);
  // 5. softmax rows in place (f32 -> bf16)
  softmax_kernel<<<BB * TQ, 256, 0, stream>>>(S);
  // 6. out = P @ V via VT
  pv_gemm<<<dim3(TQ / 128, CD / 128, BB), 256, 0, stream>>>(
      (const unsigned short*)S, vtb, out);
  // 7. overwrite K region: past_k copy + K_new; V_new
  copy_past_kernel<<<BB * TPAST * CD / 4 / 256, 256, 0, stream>>>(pk, outK);
  proj_gemm<1><<<dim3(MROWS / 128, CD / 128), 256, 0, stream>>>(xb, wkb, bk, nullptr, outK);
  proj_gemm<2><<<dim3(MROWS / 128, CD / 128), 256, 0, stream>>>(xb, wvb, bv, nullptr, outV);
}

// Round 3
// 264.382 us; speedup vs baseline: 1.4492x; 1.0411x over previous
//
#include <hip/hip_runtime.h>

// ---------------------------------------------------------------------------
// SelfAttention with KV cache, MI355X (gfx950).
// B=4, T=2048, C=1024, T_PAST=2048, T_TOT=4096.
// Mask tril(ones(T, T_total)) -> row t attends j<=t only => only past_k/v.
// Pipeline:
//   1. convert x, Wq, Wk, Wv -> bf16 in ws ; past_k -> bf16 kb in ws
//   2. v_copy_transpose: past_v -> outV rows [0,2048) AND VT bf16 [b][c][s] in ws
//   3. Q = (x Wq^T + bq)/32 -> bf16 in ws        (MFMA GEMM, m97-style)
//   4. S = Q_scaled . kb^T -> f32 in d_out K region (scratch)
//   5. softmax: read f32 row, write bf16 row IN PLACE (zeros beyond col t)
//   6. out = P(bf16) @ VT(bf16)
//   7. copy past_k -> outK[:,0:2048); K_new, V_new projections -> rows [2048,4096)
// All GEMMs: 128x128 tile, BK=32, 4 waves (2x2), global_load_lds w=16 staging
// into LINEAR LDS [128][32] (m97 structure: staging order == lane order).
// ---------------------------------------------------------------------------

typedef __bf16 bf16x8 __attribute__((ext_vector_type(8)));
typedef float f32x4 __attribute__((ext_vector_type(4)));

#define BB   4
#define TQ   2048
#define CD   1024
#define TPAST 2048
#define TTOT 4096
#define MROWS (BB * TQ)        // 8192

__device__ __forceinline__ unsigned short f32_to_bf16u(float f) {
  unsigned int u = __float_as_uint(f);
  u += 0x7FFFu + ((u >> 16) & 1u);       // RNE
  return (unsigned short)(u >> 16);
}
__device__ __forceinline__ unsigned int pack_bf16(float a, float b) {
  return (unsigned int)f32_to_bf16u(a) | ((unsigned int)f32_to_bf16u(b) << 16);
}

// async global->LDS, 16B per lane; LDS dest = wave-uniform base + lane*16
__device__ __forceinline__ void gload_lds16(const unsigned short* g,
                                            unsigned short* l) {
  __builtin_amdgcn_global_load_lds(
      (const __attribute__((address_space(1))) void*)g,
      (__attribute__((address_space(3))) void*)l, 16, 0, 0);
}

// ---- f32 -> bf16 bulk convert (float4 in, uint2 out) -----------------------
__global__ __launch_bounds__(256) void cvt_f32_bf16_kernel(
    const float* __restrict__ src, unsigned short* __restrict__ dst, int n4) {
  int i = blockIdx.x * 256 + threadIdx.x;
  if (i >= n4) return;
  float4 f = ((const float4*)src)[i];
  uint2 o;
  o.x = pack_bf16(f.x, f.y);
  o.y = pack_bf16(f.z, f.w);
  ((uint2*)dst)[i] = o;
}

// ---- copy past (4,2048,1024) into cache region (4,4096,1024) rows [0,2048) -
__global__ __launch_bounds__(256) void copy_past_kernel(
    const float* __restrict__ src, float* __restrict__ dst) {
  int i = blockIdx.x * 256 + threadIdx.x;      // float4 units
  int b = i >> 19;                             // 524288 units per batch
  int rem = i & 524287;
  ((float4*)dst)[(size_t)b * 1048576 + rem] = ((const float4*)src)[i];
}

// ---- fused: past_v -> outV copy + bf16 transpose VT[b][c][s] ----------------
#define TP_PAD 134
__global__ __launch_bounds__(256) void v_copy_transpose(
    const float* __restrict__ pV, float* __restrict__ outV,
    unsigned short* __restrict__ VT) {
  __shared__ unsigned short T[32 * TP_PAD];
  const int s0 = blockIdx.x * 32, c0 = blockIdx.y * 128, b = blockIdx.z;
  const int tid = threadIdx.x;
  const int s = tid >> 3, i8 = tid & 7;
  const float* src = &pV[(size_t)(b * TPAST + s0 + s) * CD + c0];
  float* dst = &outV[(size_t)b * (TTOT * CD) + (size_t)(s0 + s) * CD + c0];
#pragma unroll
  for (int k = 0; k < 4; ++k) {
    int c = k * 32 + i8 * 4;
    float4 f = *(const float4*)&src[c];
    *(float4*)&dst[c] = f;
    *(unsigned int*)&T[s * TP_PAD + c]     = pack_bf16(f.x, f.y);
    *(unsigned int*)&T[s * TP_PAD + c + 2] = pack_bf16(f.z, f.w);
  }
  __syncthreads();
  const int c = tid >> 2, sq = tid & 3;
#pragma unroll
  for (int ii = 0; ii < 2; ++ii) {
    int cc = c + ii * 64;
    unsigned short tmp[8];
#pragma unroll
    for (int j = 0; j < 8; ++j) tmp[j] = T[(sq * 8 + j) * TP_PAD + cc];
    *(uint4*)&VT[(size_t)(b * CD + c0 + cc) * TPAST + s0 + sq * 8] = *(uint4*)tmp;
  }
}

// ---- projection GEMM: Y = x @ W^T + b ; M=8192, N=1024, K=1024 -------------
// MODE 0: Y -> bf16 Q (scaled by 1/32).  MODE 1/2: Y -> f32 cache rows 2048+.
template <int MODE>
__global__ __launch_bounds__(256) void proj_gemm(
    const unsigned short* __restrict__ A,   // x bf16 [8192][1024]
    const unsigned short* __restrict__ W,   // W bf16 [1024][1024]
    const float* __restrict__ bias,
    unsigned short* __restrict__ outQ,      // MODE 0
    float* __restrict__ outF) {             // MODE 1/2: cache region base
  __shared__ unsigned short sA[128 * 32];   // linear, rows of 64B
  __shared__ unsigned short sB[128 * 32];
  const int tm = blockIdx.x * 128, tn = blockIdx.y * 128;
  const int tid = threadIdx.x, lane = tid & 63, wv = tid >> 6;
  const int wr = wv >> 1, wc = wv & 1;
  const int gr = lane >> 2, gc = (lane & 3) * 8;   // lane's slot in 16-row chunk
  const unsigned short* aSrc = &A[(size_t)(tm + wv * 32 + gr) * CD + gc];
  const unsigned short* bSrc = &W[(size_t)(tn + wv * 32 + gr) * CD + gc];
  unsigned short* aDst = &sA[wv * 32 * 32];
  unsigned short* bDst = &sB[wv * 32 * 32];
  f32x4 acc[4][4] = {};
  for (int k0 = 0; k0 < CD; k0 += 32) {
    gload_lds16(aSrc + k0, aDst);
    gload_lds16(aSrc + k0 + (size_t)16 * CD, aDst + 16 * 32);
    gload_lds16(bSrc + k0, bDst);
    gload_lds16(bSrc + k0 + (size_t)16 * CD, bDst + 16 * 32);
    __syncthreads();
    bf16x8 af[4], bg[4];
    const int koff = (lane >> 4) * 8;
#pragma unroll
    for (int i = 0; i < 4; ++i)
      af[i] = *(const bf16x8*)&sA[(wr * 64 + i * 16 + (lane & 15)) * 32 + koff];
#pragma unroll
    for (int i = 0; i < 4; ++i)
      bg[i] = *(const bf16x8*)&sB[(wc * 64 + i * 16 + (lane & 15)) * 32 + koff];
#pragma unroll
    for (int mi = 0; mi < 4; ++mi)
#pragma unroll
      for (int ni = 0; ni < 4; ++ni)
        acc[mi][ni] = __builtin_amdgcn_mfma_f32_16x16x32_bf16(
            af[mi], bg[ni], acc[mi][ni], 0, 0, 0);
    __syncthreads();
  }
  const int rsub = (lane >> 4) * 4, csub = lane & 15;
#pragma unroll
  for (int mi = 0; mi < 4; ++mi)
#pragma unroll
    for (int ni = 0; ni < 4; ++ni) {
      int gcn = tn + wc * 64 + ni * 16 + csub;
      float bv = bias[gcn];
#pragma unroll
      for (int r = 0; r < 4; ++r) {
        int grw = tm + wr * 64 + mi * 16 + rsub + r;
        float v = acc[mi][ni][r] + bv;
        if (MODE == 0) {
          outQ[(size_t)grw * CD + gcn] = f32_to_bf16u(v * 0.03125f);  // 1/sqrt(1024)
        } else {
          int b = grw >> 11, t = grw & (TQ - 1);
          outF[(size_t)b * (TTOT * CD) + (size_t)(TPAST + t) * CD + gcn] = v;
        }
      }
    }
}

// ---- scores: S[b][t][s] = Q_scaled[b,t,:] . kb[b,s,:] ----------------------
__global__ __launch_bounds__(256) void score_gemm(
    const unsigned short* __restrict__ Q,   // bf16 [8192][1024], pre-scaled
    const unsigned short* __restrict__ KB,  // bf16 [4][2048][1024]
    float* __restrict__ S) {                // f32 [4][2048][2048]
  const int t0 = blockIdx.x * 128, s0 = blockIdx.y * 128, b = blockIdx.z;
  if (s0 > t0 + 127) return;
  __shared__ unsigned short sA[128 * 32];
  __shared__ unsigned short sB[128 * 32];
  const int tid = threadIdx.x, lane = tid & 63, wv = tid >> 6;
  const int wr = wv >> 1, wc = wv & 1;
  const int gr = lane >> 2, gc = (lane & 3) * 8;
  const unsigned short* aSrc = &Q[(size_t)(b * TQ + t0 + wv * 32 + gr) * CD + gc];
  const unsigned short* bSrc = &KB[(size_t)(b * TPAST + s0 + wv * 32 + gr) * CD + gc];
  unsigned short* aDst = &sA[wv * 32 * 32];
  unsigned short* bDst = &sB[wv * 32 * 32];
  f32x4 acc[4][4] = {};
  for (int k0 = 0; k0 < CD; k0 += 32) {
    gload_lds16(aSrc + k0, aDst);
    gload_lds16(aSrc + k0 + (size_t)16 * CD, aDst + 16 * 32);
    gload_lds16(bSrc + k0, bDst);
    gload_lds16(bSrc + k0 + (size_t)16 * CD, bDst + 16 * 32);
    __syncthreads();
    bf16x8 af[4], bg[4];
    const int koff = (lane >> 4) * 8;
#pragma unroll
    for (int i = 0; i < 4; ++i)
      af[i] = *(const bf16x8*)&sA[(wr * 64 + i * 16 + (lane & 15)) * 32 + koff];
#pragma unroll
    for (int i = 0; i < 4; ++i)
      bg[i] = *(const bf16x8*)&sB[(wc * 64 + i * 16 + (lane & 15)) * 32 + koff];
#pragma unroll
    for (int mi = 0; mi < 4; ++mi)
#pragma unroll
      for (int ni = 0; ni < 4; ++ni)
        acc[mi][ni] = __builtin_amdgcn_mfma_f32_16x16x32_bf16(
            af[mi], bg[ni], acc[mi][ni], 0, 0, 0);
    __syncthreads();
  }
  const int rsub = (lane >> 4) * 4, csub = lane & 15;
#pragma unroll
  for (int mi = 0; mi < 4; ++mi)
#pragma unroll
    for (int ni = 0; ni < 4; ++ni) {
      int gs = s0 + wc * 64 + ni * 16 + csub;
#pragma unroll
      for (int r = 0; r < 4; ++r) {
        int gt = t0 + wr * 64 + mi * 16 + rsub + r;
        S[(size_t)b * (TQ * TPAST) + (size_t)gt * TPAST + gs] = acc[mi][ni][r];
      }
    }
}

// ---- row softmax: read f32 row, write bf16 row IN PLACE (first 4096B) ------
__global__ __launch_bounds__(256) void softmax_kernel(float* __restrict__ S) {
  const int row = blockIdx.x;               // 0..8191
  const int b = row >> 11, t = row & (TQ - 1);
  float* p = S + (size_t)b * (TQ * TPAST) + (size_t)t * TPAST;
  const int tid = threadIdx.x, lane = tid & 63, wv = tid >> 6;
  __shared__ float red[8];
  const int base = tid * 8;
  float4 f0 = *(const float4*)&p[base];
  float4 f1 = *(const float4*)&p[base + 4];
  float v[8] = {f0.x, f0.y, f0.z, f0.w, f1.x, f1.y, f1.z, f1.w};
  float m = -3.0e38f;
#pragma unroll
  for (int i = 0; i < 8; ++i) {
    if (base + i > t) v[i] = -3.0e38f;      // masked/unwritten cols
    m = fmaxf(m, v[i]);
  }
#pragma unroll
  for (int off = 32; off >= 1; off >>= 1) m = fmaxf(m, __shfl_down(m, off));
  if (lane == 0) red[wv] = m;
  __syncthreads();
  if (tid == 0) red[4] = fmaxf(fmaxf(red[0], red[1]), fmaxf(red[2], red[3]));
  __syncthreads();
  const float rm = red[4];
  float e[8], s = 0.f;
#pragma unroll
  for (int i = 0; i < 8; ++i) {
    e[i] = (base + i <= t) ? __expf(v[i] - rm) : 0.f;
    s += e[i];
  }
#pragma unroll
  for (int off = 32; off >= 1; off >>= 1) s += __shfl_down(s, off);
  __syncthreads();
  if (lane == 0) red[wv] = s;
  __syncthreads();
  if (tid == 0) red[5] = red[0] + red[1] + red[2] + red[3];
  __syncthreads();                           // also orders all reads before writes
  const float inv = 1.f / red[5];
  unsigned short ob[8];
#pragma unroll
  for (int i = 0; i < 8; ++i) ob[i] = f32_to_bf16u(e[i] * inv);
  *(uint4*)&((unsigned short*)p)[base] = *(uint4*)ob;
}

// ---- out = P(bf16) @ VT(bf16) ; per batch M=2048, N=1024(c), K=s -----------
__global__ __launch_bounds__(256) void pv_gemm(
    const unsigned short* __restrict__ Pb,  // bf16 rows at f32-row byte offsets
    const unsigned short* __restrict__ VT,  // bf16 [4][1024][2048]
    float* __restrict__ O) {                // f32 [4][2048][1024]
  const int t0 = blockIdx.x * 128, c0 = blockIdx.y * 128, b = blockIdx.z;
  __shared__ unsigned short sA[128 * 32];
  __shared__ unsigned short sB[128 * 32];
  const int tid = threadIdx.x, lane = tid & 63, wv = tid >> 6;
  const int wr = wv >> 1, wc = wv & 1;
  const int gr = lane >> 2, gc = (lane & 3) * 8;
  // P bf16 row for t lives at u16 offset 2*TPAST*(b*TQ + t), cols packed from 0
  const unsigned short* aSrc =
      &Pb[(size_t)(b * TQ + t0 + wv * 32 + gr) * (2 * TPAST) + gc];
  const unsigned short* bSrc =
      &VT[(size_t)(b * CD + c0 + wv * 32 + gr) * TPAST + gc];
  unsigned short* aDst = &sA[wv * 32 * 32];
  unsigned short* bDst = &sB[wv * 32 * 32];
  f32x4 acc[4][4] = {};
  const int s_end = (t0 + 128 < TPAST) ? (t0 + 128) : TPAST;  // P==0 past t
  for (int s0 = 0; s0 < s_end; s0 += 32) {
    gload_lds16(aSrc + s0, aDst);
    gload_lds16(aSrc + s0 + (size_t)16 * (2 * TPAST), aDst + 16 * 32);
    gload_lds16(bSrc + s0, bDst);
    gload_lds16(bSrc + s0 + (size_t)16 * TPAST, bDst + 16 * 32);
    __syncthreads();
    bf16x8 af[4], bg[4];
    const int koff = (lane >> 4) * 8;
#pragma unroll
    for (int i = 0; i < 4; ++i)
      af[i] = *(const bf16x8*)&sA[(wr * 64 + i * 16 + (lane & 15)) * 32 + koff];
#pragma unroll
    for (int i = 0; i < 4; ++i)
      bg[i] = *(const bf16x8*)&sB[(wc * 64 + i * 16 + (lane & 15)) * 32 + koff];
#pragma unroll
    for (int mi = 0; mi < 4; ++mi)
#pragma unroll
      for (int ni = 0; ni < 4; ++ni)
        acc[mi][ni] = __builtin_amdgcn_mfma_f32_16x16x32_bf16(
            af[mi], bg[ni], acc[mi][ni], 0, 0, 0);
    __syncthreads();
  }
  const int rsub = (lane >> 4) * 4, csub = lane & 15;
#pragma unroll
  for (int mi = 0; mi < 4; ++mi)
#pragma unroll
    for (int ni = 0; ni < 4; ++ni) {
      int gcn = c0 + wc * 64 + ni * 16 + csub;
#pragma unroll
      for (int r = 0; r < 4; ++r) {
        int gt = t0 + wr * 64 + mi * 16 + rsub + r;
        O[(size_t)(b * TQ + gt) * CD + gcn] = acc[mi][ni][r];
      }
    }
}

extern "C" void kernel_launch(void* const* d_in, const int* in_sizes, int n_in,
                              void* d_out, int out_size, void* d_ws, size_t ws_size,
                              hipStream_t stream) {
  const float* x  = (const float*)d_in[0];
  const float* pk = (const float*)d_in[1];
  const float* pv = (const float*)d_in[2];
  const float* Wq = (const float*)d_in[3];
  const float* bq = (const float*)d_in[4];
  const float* Wk = (const float*)d_in[5];
  const float* bk = (const float*)d_in[6];
  const float* Wv = (const float*)d_in[7];
  const float* bv = (const float*)d_in[8];

  float* out  = (float*)d_out;                       // (4,2048,1024)
  float* outK = out + (size_t)BB * TQ * CD;          // (4,4096,1024)
  float* outV = outK + (size_t)BB * TTOT * CD;       // (4,4096,1024)
  float* S = outK;  // 67.1MB scratch == K region size; overwritten in step 7

  unsigned short* xb  = (unsigned short*)d_ws;       // 8192*1024 bf16
  unsigned short* wqb = xb + (size_t)MROWS * CD;
  unsigned short* wkb = wqb + (size_t)CD * CD;
  unsigned short* wvb = wkb + (size_t)CD * CD;
  unsigned short* qb  = wvb + (size_t)CD * CD;       // 8192*1024 bf16
  unsigned short* vtb = qb + (size_t)MROWS * CD;     // 4*1024*2048 bf16 (V^T)
  unsigned short* kb  = vtb + (size_t)BB * CD * TPAST; // 4*2048*1024 bf16

  // 1. conversions
  cvt_f32_bf16_kernel<<<MROWS * CD / 4 / 256, 256, 0, stream>>>(x, xb, MROWS * CD / 4);
  cvt_f32_bf16_kernel<<<CD * CD / 4 / 256, 256, 0, stream>>>(Wq, wqb, CD * CD / 4);
  cvt_f32_bf16_kernel<<<CD * CD / 4 / 256, 256, 0, stream>>>(Wk, wkb, CD * CD / 4);
  cvt_f32_bf16_kernel<<<CD * CD / 4 / 256, 256, 0, stream>>>(Wv, wvb, CD * CD / 4);
  cvt_f32_bf16_kernel<<<BB * TPAST * CD / 4 / 256, 256, 0, stream>>>(
      pk, kb, BB * TPAST * CD / 4);
  // 2. past_v -> outV rows [0,2048) + VT bf16 transpose
  v_copy_transpose<<<dim3(TPAST / 32, CD / 128, BB), 256, 0, stream>>>(pv, outV, vtb);
  // 3. Q projection (scaled, bf16)
  proj_gemm<0><<<dim3(MROWS / 128, CD / 128), 256, 0, stream>>>(xb, wqb, bq, qb, nullptr);
  // 4. scores into S (K-region scratch)
  score_gemm<<<dim3(TQ / 128, TPAST / 128, BB), 256, 0, stream>>>(qb, kb, S);
  // 5. softmax rows in place (f32 -> bf16)
  softmax_kernel<<<BB * TQ, 256, 0, stream>>>(S);
  // 6. out = P @ V via VT
  pv_gemm<<<dim3(TQ / 128, CD / 128, BB), 256, 0, stream>>>(
      (const unsigned short*)S, vtb, out);
  // 7. overwrite K region: past_k copy + K_new; V_new
  copy_past_kernel<<<BB * TPAST * CD / 4 / 256, 256, 0, stream>>>(pk, outK);
  proj_gemm<1><<<dim3(MROWS / 128, CD / 128), 256, 0, stream>>>(xb, wkb, bk, nullptr, outK);
  proj_gemm<2><<<dim3(MROWS / 128, CD / 128), 256, 0, stream>>>(xb, wvb, bv, nullptr, outV);
}